// Round 3
// baseline (143.408 us; speedup 1.0000x reference)
//
#include <hip/hip_runtime.h>
#include <math.h>

#define BB 4
#define NN 128
#define MM 16
#define KK 80
#define CF 256
#define CSL 2048
#define CT 2304      // CF + CSL
#define TFAST 32
#define TSLOW 8
#define HH 14
#define WW 14
#define HWQ 196      // 14*14
#define NQ4 49       // HWQ/4 float4 per (b,c)

// ---- workspace layout (float offsets) ----
#define FEAT_OFF   0
#define FEAT_SIZE  (BB*CT*HWQ)            // 1,806,336  [b][c][hw]
#define G_OFF      (FEAT_OFF + FEAT_SIZE)
#define G_SIZE     (BB*HWQ*KK)            // 62,720     [b][cell][k]
#define FGF_OFF    (G_OFF + G_SIZE)       // 512 floats
#define ASSIGN_OFF (FGF_OFF + BB*NN)      // 512 ints (stored in float slots)
#define NUM_OFF    (ASSIGN_OFF + BB*NN)   // 4
#define CNT_OFF    (NUM_OFF + BB)         // 4
#define CTR_OFF    (CNT_OFF + BB)         // 1 int (completion counter)
#define P_OFF      (CTR_OFF + 8)          // padded

#define NSPLIT 32
#define CCH    (CT/NSPLIT)                // 72 channels per split
#define P_SIZE (NSPLIT*G_SIZE)            // 2,007,040 floats = 8 MB

// ---------------- K1: temporal mean (+ zero G for atomic fallback) ----------------
__global__ __launch_bounds__(256) void k1_tmean(const float* __restrict__ fast,
                                                const float* __restrict__ slow,
                                                float* __restrict__ ws) {
    int idx = blockIdx.x * blockDim.x + threadIdx.x;
    if (idx < G_SIZE) ws[G_OFF + idx] = 0.f;
    const int total = BB * CT * NQ4;                   // 451,584
    if (idx >= total) return;
    int q  = idx % NQ4;
    int bc = idx / NQ4;
    int c  = bc % CT;
    int b  = bc / CT;
    float4 acc = make_float4(0.f, 0.f, 0.f, 0.f);
    if (c < CF) {
        const float4* p = (const float4*)(fast + (size_t)(b*CF + c) * TFAST * HWQ) + q;
        #pragma unroll 8
        for (int t = 0; t < TFAST; ++t) {
            float4 v = p[t * (HWQ/4)];
            acc.x += v.x; acc.y += v.y; acc.z += v.z; acc.w += v.w;
        }
        const float s = 1.f / TFAST;
        acc.x *= s; acc.y *= s; acc.z *= s; acc.w *= s;
    } else {
        const float4* p = (const float4*)(slow + (size_t)(b*CSL + (c-CF)) * TSLOW * HWQ) + q;
        #pragma unroll
        for (int t = 0; t < TSLOW; ++t) {
            float4 v = p[t * (HWQ/4)];
            acc.x += v.x; acc.y += v.y; acc.z += v.z; acc.w += v.w;
        }
        const float s = 1.f / TSLOW;
        acc.x *= s; acc.y *= s; acc.z *= s; acc.w *= s;
    }
    ((float4*)(ws + FEAT_OFF))[bc * NQ4 + q] = acc;
}

// ---------------- K2: LDS-tiled split-C GEMM ----------------
// grid 256 = b(4) x khalf(2) x csplit(32); block 256 threads.
__global__ __launch_bounds__(256) void k2_gemm(const float* __restrict__ Wc,
                                               float* __restrict__ ws,
                                               int use_partials) {
    __shared__ float sfeat[CCH*HWQ];   // 56,448 B
    __shared__ float sW[CCH*KK];       // 23,040 B
    int bid = blockIdx.x;
    int b  = bid >> 6;
    int r  = bid & 63;
    int kh = r >> 5;
    int cs = r & 31;
    int c0 = cs * CCH;
    int tid = threadIdx.x;

    const float4* fsrc = (const float4*)(ws + FEAT_OFF + (size_t)(b*CT + c0) * HWQ);
    float4* fdst = (float4*)sfeat;
    #pragma unroll
    for (int i = 0; i < 14; ++i) {
        int x = tid + i*256;
        if (x < CCH*HWQ/4) fdst[x] = fsrc[x];
    }
    const float4* wsrc = (const float4*)(Wc + c0*KK);
    float4* wdst = (float4*)sW;
    #pragma unroll
    for (int i = 0; i < 6; ++i) {
        int x = tid + i*256;
        if (x < CCH*KK/4) wdst[x] = wsrc[x];
    }
    __syncthreads();

    int kq = tid & 7;
    int cg = tid >> 3;                                 // 0..31
    float acc[7][5];
    #pragma unroll
    for (int j = 0; j < 7; ++j)
        #pragma unroll
        for (int i = 0; i < 5; ++i) acc[j][i] = 0.f;

    const float* fr = sfeat + cg;
    const float* wr = sW + kh*40 + kq*5;
    #pragma unroll 2
    for (int c = 0; c < CCH; ++c) {
        float w0 = wr[c*KK+0], w1 = wr[c*KK+1], w2 = wr[c*KK+2],
              w3 = wr[c*KK+3], w4 = wr[c*KK+4];
        #pragma unroll
        for (int j = 0; j < 7; ++j) {
            float fv = fr[c*HWQ + 32*j];   // j==6,cg>=4 reads into sW: harmless, never stored
            acc[j][0] += fv*w0; acc[j][1] += fv*w1; acc[j][2] += fv*w2;
            acc[j][3] += fv*w3; acc[j][4] += fv*w4;
        }
    }

    int k0 = kh*40 + kq*5;
    if (use_partials) {
        float* P = ws + P_OFF + (size_t)cs*G_SIZE + (size_t)b*HWQ*KK;
        #pragma unroll
        for (int j = 0; j < 7; ++j) {
            int cell = cg + 32*j;
            if (cell < HWQ) {
                #pragma unroll
                for (int i = 0; i < 5; ++i) P[cell*KK + k0 + i] = acc[j][i];
            }
        }
    } else {
        float* g = ws + G_OFF + (size_t)b*HWQ*KK;
        #pragma unroll
        for (int j = 0; j < 7; ++j) {
            int cell = cg + 32*j;
            if (cell < HWQ) {
                #pragma unroll
                for (int i = 0; i < 5; ++i) atomicAdd(&g[cell*KK + k0 + i], acc[j][i]);
            }
        }
    }
}

// ---------------- K2b: reduce partials (blocks 0..122) + IoU assignment (block 123) ----
#define RED_BLOCKS ((G_SIZE + 511) / 512)   // 123
__global__ __launch_bounds__(512) void k2b_assign(const float* __restrict__ props,
                                                  const float* __restrict__ gtb,
                                                  float* __restrict__ ws,
                                                  int use_partials) {
    int blk = blockIdx.x;
    int t = threadIdx.x;
    if (blk < RED_BLOCKS) {
        if (!use_partials) return;          // atomic fallback already produced G
        int idx = blk * 512 + t;
        if (idx < G_SIZE) {
            const float* P = ws + P_OFF;
            float s = 0.f;
            #pragma unroll
            for (int cs = 0; cs < NSPLIT; ++cs) s += P[(size_t)cs*G_SIZE + idx];
            ws[G_OFF + idx] = s;
        }
        return;
    }
    // ---- assignment block (512 threads = B*N) ----
    __shared__ float sgt[BB*MM*4];
    __shared__ float sfg[BB*NN];
    __shared__ int sany;
    if (t < BB*MM*4) sgt[t] = gtb[t];
    if (t == 0) sany = 0;
    __syncthreads();
    int b = t >> 7;
    float x1 = props[t*4+0], y1 = props[t*4+1], x2 = props[t*4+2], y2 = props[t*4+3];
    float aa = (x2 - x1) * (y2 - y1);
    float best = -1.f; int arg = 0;
    for (int m = 0; m < MM; ++m) {
        const float* g = &sgt[(b*MM + m)*4];
        float tlx = fmaxf(x1, g[0]), tly = fmaxf(y1, g[1]);
        float brx = fminf(x2, g[2]), bry = fminf(y2, g[3]);
        float inter = fmaxf(brx - tlx, 0.f) * fmaxf(bry - tly, 0.f);
        float ab = (g[2] - g[0]) * (g[3] - g[1]);
        float iou = inter / (aa + ab - inter);
        if (iou > best) { best = iou; arg = m; }   // first-max = argmax semantics
    }
    if (best >= 0.85f) atomicOr(&sany, 1);
    __syncthreads();
    float fg = sany ? (best >= 0.85f ? 1.f : 0.f) : (best >= 0.5f ? 1.f : 0.f);
    sfg[t] = fg;
    ws[FGF_OFF + t] = fg;
    ((int*)ws)[ASSIGN_OFF + t] = arg;
    __syncthreads();
    if (t < BB) {
        float s = 0.f;
        for (int i = 0; i < NN; ++i) s += sfg[t*NN + i];
        ws[CNT_OFF + t] = s;
        ws[NUM_OFF + t] = 0.f;
    }
    if (t == 0) ((int*)ws)[CTR_OFF] = 0;
}

// ---------------- K3b: per-proposal loss + last-block finalize ----------------
__device__ __forceinline__ float logsig(float x) {
    return fminf(x, 0.f) - log1pf(expf(-fabsf(x)));
}

__global__ __launch_bounds__(128) void k3b_loss(const float* __restrict__ props,
                                                const float* __restrict__ gtc,
                                                const float* __restrict__ bcls,
                                                float* __restrict__ ws,
                                                float* __restrict__ out) {
    int p = blockIdx.x;
    int b = p >> 7;
    int t = threadIdx.x;
    __shared__ int cells[49];
    __shared__ float red[128];
    if (ws[FGF_OFF + p] != 0.f) {           // fg: compute loss contribution
        if (t < 49) {
            int gy = t / 7, gx = t % 7;
            float x1 = props[p*4+0] * (1.f/16.f);
            float y1 = props[p*4+1] * (1.f/16.f);
            float x2 = props[p*4+2] * (1.f/16.f);
            float y2 = props[p*4+3] * (1.f/16.f);
            float gry = ((float)gy + 0.5f) / 7.f;
            float grx = ((float)gx + 0.5f) / 7.f;
            float cy = y1 + gry * (y2 - y1);
            float cx = x1 + grx * (x2 - x1);
            int iy = (int)floorf(cy); iy = min(max(iy, 0), HH-1);
            int ix = (int)floorf(cx); ix = min(max(ix, 0), WW-1);
            cells[t] = iy * WW + ix;
        }
        __syncthreads();
        float lk = 0.f;
        if (t < KK) {
            float acc = 0.f;
            const float* Gb = ws + G_OFF + b * HWQ * KK + t;
            #pragma unroll 7
            for (int g = 0; g < 49; ++g) acc += Gb[cells[g] * KK];
            float logit = acc * (1.f/49.f) + bcls[t];
            int a = ((const int*)ws)[ASSIGN_OFF + p];
            float y = gtc[(b*MM + a)*KK + t];
            lk = -(y * logsig(logit) + (1.f - y) * logsig(-logit));
        }
        red[t] = lk;
        __syncthreads();
        for (int s = 64; s > 0; s >>= 1) {
            if (t < s) red[t] += red[t + s];
            __syncthreads();
        }
        if (t == 0) atomicAdd(&ws[NUM_OFF + b], red[0] * (1.f/KK));
    }
    // completion counter: every block bumps exactly once; last finalizes out[]
    if (t == 0) {
        __threadfence();
        int old = atomicAdd(&((int*)ws)[CTR_OFF], 1);
        if (old == BB*NN - 1) {
            __threadfence();
            #pragma unroll
            for (int bb = 0; bb < BB; ++bb) {
                float num = atomicAdd(&ws[NUM_OFF + bb], 0.f);   // coherent read
                float c = ws[CNT_OFF + bb];
                out[bb] = (c > 0.f) ? num / c : 0.f;
            }
        }
    }
}

extern "C" void kernel_launch(void* const* d_in, const int* in_sizes, int n_in,
                              void* d_out, int out_size, void* d_ws, size_t ws_size,
                              hipStream_t stream) {
    const float* fast  = (const float*)d_in[0];
    const float* slow  = (const float*)d_in[1];
    const float* props = (const float*)d_in[2];
    const float* gtb   = (const float*)d_in[3];
    const float* gtc   = (const float*)d_in[4];
    const float* Wc    = (const float*)d_in[5];
    const float* bcls  = (const float*)d_in[6];
    float* ws  = (float*)d_ws;
    float* out = (float*)d_out;

    const size_t need = (size_t)(P_OFF + P_SIZE) * sizeof(float);
    const int use_partials = (ws_size >= need) ? 1 : 0;   // deterministic -> graph-safe

    const int k1_threads = BB * CT * NQ4;              // 451,584
    k1_tmean<<<(k1_threads + 255)/256, 256, 0, stream>>>(fast, slow, ws);
    k2_gemm<<<BB * 2 * NSPLIT, 256, 0, stream>>>(Wc, ws, use_partials);
    k2b_assign<<<RED_BLOCKS + 1, 512, 0, stream>>>(props, gtb, ws, use_partials);
    k3b_loss<<<BB*NN, 128, 0, stream>>>(props, gtc, bcls, ws, out);
}

// Round 4
// 134.025 us; speedup vs baseline: 1.0700x; 1.0700x over previous
//
#include <hip/hip_runtime.h>
#include <math.h>

#define BB 4
#define NN 128
#define MM 16
#define KK 80
#define CF 256
#define CSL 2048
#define CT 2304      // CF + CSL
#define TFAST 32
#define TSLOW 8
#define HH 14
#define WW 14
#define HWQ 196      // 14*14
#define NQ4 49       // HWQ/4 float4 per (b,c)

// ---- workspace layout (float offsets) ----
#define G_OFF      0
#define G_SIZE     (BB*HWQ*KK)            // 62,720     [b][cell][k]
#define FGF_OFF    (G_OFF + G_SIZE)       // 512 floats
#define ASSIGN_OFF (FGF_OFF + BB*NN)      // 512 ints (in float slots)
#define NUM_OFF    (ASSIGN_OFF + BB*NN)   // 4
#define CNT_OFF    (NUM_OFF + BB)         // 4
#define CTR_OFF    (CNT_OFF + BB)         // 1 int
#define P_OFF      (CTR_OFF + 8)          // padded

#define NSPLIT 64                          // chunks per b == partial count
#define MAXCH  43
#define P_SIZE (NSPLIT*G_SIZE)            // 4,014,080 floats = 16 MB

// ---------------- K12: fused temporal-mean + split-C GEMM ----------------
// grid 256 = b(4) x chunk(64). Chunk table (per b): r<16 -> fast, 16 ch;
// r>=16 -> slow, 43 ch (32 chunks) then 42 ch (16 chunks). Block stages the
// temporal mean of its chunk into LDS (reads raw fast/slow once), stages W,
// then computes partial G for all 196 cells x 80 k.
// Thread map: cg = tid&31 (cells cg+32j, j<7), kq = tid>>5 (k = kq*10..+9).
// P layout [cs][b][k][cell] -> stores coalesce over cg.
__global__ __launch_bounds__(256) void k12_fused(const float* __restrict__ fastp,
                                                 const float* __restrict__ slowp,
                                                 const float* __restrict__ Wc,
                                                 float* __restrict__ ws,
                                                 int use_partials) {
    __shared__ float sfeat[MAXCH*HWQ + 64];   // +64 pad: j==6 overread guard
    __shared__ float sW[MAXCH*KK];
    int bid = blockIdx.x;
    int b = bid >> 6;
    int r = bid & 63;
    int gc0, nch, T, isfast;
    if (r < 16) { isfast = 1; gc0 = r * 16; nch = 16; T = TFAST; }
    else {
        int s = r - 16;
        int c0s = (s < 32) ? (43 * s) : (1376 + 42 * (s - 32));
        nch = (s < 32) ? 43 : 42;
        gc0 = CF + c0s; T = TSLOW; isfast = 0;
    }
    int tid = threadIdx.x;

    // ---- stage temporal mean of this chunk into sfeat[cl][hw] ----
    const float4* base = isfast
        ? ((const float4*)fastp + (size_t)(b * CF + gc0) * TFAST * NQ4)
        : ((const float4*)slowp + (size_t)(b * CSL + (gc0 - CF)) * TSLOW * NQ4);
    const float scale = 1.f / (float)T;
    int ntasks = nch * NQ4;
    for (int x = tid; x < ntasks; x += 256) {
        int cl = x / NQ4;
        int q  = x - cl * NQ4;
        const float4* p = base + (size_t)cl * T * NQ4 + q;
        float4 a = make_float4(0.f, 0.f, 0.f, 0.f);
        #pragma unroll 8
        for (int t = 0; t < T; ++t) {
            float4 v = p[t * NQ4];
            a.x += v.x; a.y += v.y; a.z += v.z; a.w += v.w;
        }
        a.x *= scale; a.y *= scale; a.z *= scale; a.w *= scale;
        ((float4*)sfeat)[cl * NQ4 + q] = a;
    }
    // ---- stage W rows [gc0, gc0+nch) ----
    const float4* wsrc = (const float4*)Wc + (size_t)gc0 * (KK / 4);
    int wtasks = nch * (KK / 4);
    for (int x = tid; x < wtasks; x += 256) ((float4*)sW)[x] = wsrc[x];
    __syncthreads();

    // ---- GEMM: partial G over this chunk's channels ----
    int cg = tid & 31;
    int kq = tid >> 5;            // 0..7, k0 = kq*10
    float acc[7][10];
    #pragma unroll
    for (int j = 0; j < 7; ++j)
        #pragma unroll
        for (int i = 0; i < 10; ++i) acc[j][i] = 0.f;

    const float* fr = sfeat + cg;
    const float* wr = sW + kq * 10;
    for (int c = 0; c < nch; ++c) {
        float w[10];
        #pragma unroll
        for (int i = 0; i < 10; ++i) w[i] = wr[c * KK + i];
        #pragma unroll
        for (int j = 0; j < 7; ++j) {
            float fv = fr[c * HWQ + 32 * j];   // j==6,cg>=4 hits pad: never stored
            #pragma unroll
            for (int i = 0; i < 10; ++i) acc[j][i] += fv * w[i];
        }
    }

    int k0 = kq * 10;
    if (use_partials) {
        // P[r][b][k][cell] — coalesced over cg
        float* P = ws + P_OFF + (size_t)r * G_SIZE + (size_t)b * (KK * HWQ);
        #pragma unroll
        for (int j = 0; j < 7; ++j) {
            int cell = cg + 32 * j;
            if (cell < HWQ) {
                #pragma unroll
                for (int i = 0; i < 10; ++i) P[(k0 + i) * HWQ + cell] = acc[j][i];
            }
        }
    } else {
        float* g = ws + G_OFF + (size_t)b * HWQ * KK;
        #pragma unroll
        for (int j = 0; j < 7; ++j) {
            int cell = cg + 32 * j;
            if (cell < HWQ) {
                #pragma unroll
                for (int i = 0; i < 10; ++i) atomicAdd(&g[cell * KK + k0 + i], acc[j][i]);
            }
        }
    }
}

// ---------------- fallback: zero G (only when ws too small for P) ----------------
__global__ __launch_bounds__(256) void kz_zero(float* __restrict__ ws) {
    int idx = blockIdx.x * 256 + threadIdx.x;
    if (idx < G_SIZE) ws[G_OFF + idx] = 0.f;
}

// ---------------- K2b: reduce partials (blocks 0..122) + IoU assign (block 123) ----
#define RED_BLOCKS ((G_SIZE + 511) / 512)   // 123
__global__ __launch_bounds__(512) void k2b_assign(const float* __restrict__ props,
                                                  const float* __restrict__ gtb,
                                                  float* __restrict__ ws,
                                                  int use_partials) {
    int blk = blockIdx.x;
    int t = threadIdx.x;
    if (blk < RED_BLOCKS) {
        if (!use_partials) return;
        int ridx = blk * 512 + t;            // linear over [b][k][cell]
        if (ridx < G_SIZE) {
            const float* P = ws + P_OFF;
            float s = 0.f;
            #pragma unroll 16
            for (int cs = 0; cs < NSPLIT; ++cs) s += P[(size_t)cs * G_SIZE + ridx];
            int b    = ridx / (KK * HWQ);
            int rem  = ridx - b * (KK * HWQ);
            int k    = rem / HWQ;
            int cell = rem - k * HWQ;
            ws[G_OFF + (size_t)b * HWQ * KK + cell * KK + k] = s;  // G[b][cell][k]
        }
        return;
    }
    // ---- assignment block (512 threads = B*N) ----
    __shared__ float sgt[BB*MM*4];
    __shared__ float sfg[BB*NN];
    __shared__ int sany;
    if (t < BB*MM*4) sgt[t] = gtb[t];
    if (t == 0) sany = 0;
    __syncthreads();
    int b = t >> 7;
    float x1 = props[t*4+0], y1 = props[t*4+1], x2 = props[t*4+2], y2 = props[t*4+3];
    float aa = (x2 - x1) * (y2 - y1);
    float best = -1.f; int arg = 0;
    for (int m = 0; m < MM; ++m) {
        const float* g = &sgt[(b*MM + m)*4];
        float tlx = fmaxf(x1, g[0]), tly = fmaxf(y1, g[1]);
        float brx = fminf(x2, g[2]), bry = fminf(y2, g[3]);
        float inter = fmaxf(brx - tlx, 0.f) * fmaxf(bry - tly, 0.f);
        float ab = (g[2] - g[0]) * (g[3] - g[1]);
        float iou = inter / (aa + ab - inter);
        if (iou > best) { best = iou; arg = m; }   // first-max = argmax semantics
    }
    if (best >= 0.85f) atomicOr(&sany, 1);
    __syncthreads();
    float fg = sany ? (best >= 0.85f ? 1.f : 0.f) : (best >= 0.5f ? 1.f : 0.f);
    sfg[t] = fg;
    ws[FGF_OFF + t] = fg;
    ((int*)ws)[ASSIGN_OFF + t] = arg;
    __syncthreads();
    if (t < BB) {
        float s = 0.f;
        for (int i = 0; i < NN; ++i) s += sfg[t*NN + i];
        ws[CNT_OFF + t] = s;
        ws[NUM_OFF + t] = 0.f;
    }
    if (t == 0) ((int*)ws)[CTR_OFF] = 0;
}

// ---------------- K3b: per-proposal loss + last-block finalize ----------------
__device__ __forceinline__ float logsig(float x) {
    return fminf(x, 0.f) - log1pf(expf(-fabsf(x)));
}

__global__ __launch_bounds__(128) void k3b_loss(const float* __restrict__ props,
                                                const float* __restrict__ gtc,
                                                const float* __restrict__ bcls,
                                                float* __restrict__ ws,
                                                float* __restrict__ out) {
    int p = blockIdx.x;
    int b = p >> 7;
    int t = threadIdx.x;
    __shared__ int cells[49];
    __shared__ float red[128];
    if (ws[FGF_OFF + p] != 0.f) {
        if (t < 49) {
            int gy = t / 7, gx = t % 7;
            float x1 = props[p*4+0] * (1.f/16.f);
            float y1 = props[p*4+1] * (1.f/16.f);
            float x2 = props[p*4+2] * (1.f/16.f);
            float y2 = props[p*4+3] * (1.f/16.f);
            float gry = ((float)gy + 0.5f) / 7.f;
            float grx = ((float)gx + 0.5f) / 7.f;
            float cy = y1 + gry * (y2 - y1);
            float cx = x1 + grx * (x2 - x1);
            int iy = (int)floorf(cy); iy = min(max(iy, 0), HH-1);
            int ix = (int)floorf(cx); ix = min(max(ix, 0), WW-1);
            cells[t] = iy * WW + ix;
        }
        __syncthreads();
        float lk = 0.f;
        if (t < KK) {
            float acc = 0.f;
            const float* Gb = ws + G_OFF + b * HWQ * KK + t;
            #pragma unroll 7
            for (int g = 0; g < 49; ++g) acc += Gb[cells[g] * KK];
            float logit = acc * (1.f/49.f) + bcls[t];
            int a = ((const int*)ws)[ASSIGN_OFF + p];
            float y = gtc[(b*MM + a)*KK + t];
            lk = -(y * logsig(logit) + (1.f - y) * logsig(-logit));
        }
        red[t] = lk;
        __syncthreads();
        for (int s = 64; s > 0; s >>= 1) {
            if (t < s) red[t] += red[t + s];
            __syncthreads();
        }
        if (t == 0) atomicAdd(&ws[NUM_OFF + b], red[0] * (1.f/KK));
    }
    if (t == 0) {
        __threadfence();
        int old = atomicAdd(&((int*)ws)[CTR_OFF], 1);
        if (old == BB*NN - 1) {
            __threadfence();
            #pragma unroll
            for (int bb = 0; bb < BB; ++bb) {
                float num = atomicAdd(&ws[NUM_OFF + bb], 0.f);
                float c = ws[CNT_OFF + bb];
                out[bb] = (c > 0.f) ? num / c : 0.f;
            }
        }
    }
}

extern "C" void kernel_launch(void* const* d_in, const int* in_sizes, int n_in,
                              void* d_out, int out_size, void* d_ws, size_t ws_size,
                              hipStream_t stream) {
    const float* fastp = (const float*)d_in[0];
    const float* slowp = (const float*)d_in[1];
    const float* props = (const float*)d_in[2];
    const float* gtb   = (const float*)d_in[3];
    const float* gtc   = (const float*)d_in[4];
    const float* Wc    = (const float*)d_in[5];
    const float* bcls  = (const float*)d_in[6];
    float* ws  = (float*)d_ws;
    float* out = (float*)d_out;

    const size_t need = (size_t)(P_OFF + P_SIZE) * sizeof(float);
    const int use_partials = (ws_size >= need) ? 1 : 0;   // deterministic -> graph-safe

    if (!use_partials)
        kz_zero<<<(G_SIZE + 255)/256, 256, 0, stream>>>(ws);
    k12_fused<<<BB * NSPLIT, 256, 0, stream>>>(fastp, slowp, Wc, ws, use_partials);
    k2b_assign<<<RED_BLOCKS + 1, 512, 0, stream>>>(props, gtb, ws, use_partials);
    k3b_loss<<<BB*NN, 128, 0, stream>>>(props, gtc, bcls, ws, out);
}